// Round 1
// baseline (69025.226 us; speedup 1.0000x reference)
//
#include <hip/hip_runtime.h>
#include <hip/hip_bf16.h>
#include <hip/hip_cooperative_groups.h>

namespace cg = cooperative_groups;

// Problem constants
#define S_LEN 512
#define BATCH 64
#define IDIM 1024
#define HDIM 1024
#define NG   4096              // 4*H
#define MROWS (S_LEN*BATCH)    // 32768

// ---------------------------------------------------------------------------
// Phase 1: xW[s,b,g] = sum_i x[s,b,i] * W_w[g,i] + W_b[g]
// M=32768, N=4096, K=1024.  A=[M,K] row-major, B=[N,K] row-major (both K-fast).
// 128x128 block tile, BK=16, 8x8 per thread, 256 threads.
// ---------------------------------------------------------------------------
__global__ __launch_bounds__(256) void xw_gemm(
    const float* __restrict__ X,            // [32768,1024]
    const float* __restrict__ Wg,           // [4096,1024]
    const float* __restrict__ Wb,           // [4096]
    float* __restrict__ out_f,              // [32768,4096] (if !use_bf)
    __hip_bfloat16* __restrict__ out_b,     // same, bf16 (if use_bf)
    int use_bf)
{
    __shared__ float As[16][128];   // [k][m]
    __shared__ float Bs[16][128];   // [k][n]

    const int tid = threadIdx.x;
    const int tx = tid & 15;        // n-tile
    const int ty = tid >> 4;        // m-tile
    const int m0 = blockIdx.y * 128;
    const int n0 = blockIdx.x * 128;

    float acc[8][8];
#pragma unroll
    for (int i = 0; i < 8; ++i)
#pragma unroll
        for (int j = 0; j < 8; ++j) acc[i][j] = 0.f;

    for (int k0 = 0; k0 < IDIM; k0 += 16) {
        // stage 128x16 of A and B, transposed into [k][m]/[k][n]
#pragma unroll
        for (int c = 0; c < 2; ++c) {
            int chunk = tid + c * 256;          // 512 chunks of 4 floats
            int row = chunk >> 2;
            int kq  = chunk & 3;
            float4 av = *(const float4*)&X [(size_t)(m0 + row) * IDIM + k0 + kq * 4];
            float4 bv = *(const float4*)&Wg[(size_t)(n0 + row) * IDIM + k0 + kq * 4];
            As[kq*4+0][row] = av.x; As[kq*4+1][row] = av.y;
            As[kq*4+2][row] = av.z; As[kq*4+3][row] = av.w;
            Bs[kq*4+0][row] = bv.x; Bs[kq*4+1][row] = bv.y;
            Bs[kq*4+2][row] = bv.z; Bs[kq*4+3][row] = bv.w;
        }
        __syncthreads();

#pragma unroll
        for (int kk = 0; kk < 16; ++kk) {
            float4 a0 = *(const float4*)&As[kk][ty*4];
            float4 a1 = *(const float4*)&As[kk][64 + ty*4];
            float4 b0 = *(const float4*)&Bs[kk][tx*4];
            float4 b1 = *(const float4*)&Bs[kk][64 + tx*4];
            float am[8] = {a0.x,a0.y,a0.z,a0.w,a1.x,a1.y,a1.z,a1.w};
            float bn[8] = {b0.x,b0.y,b0.z,b0.w,b1.x,b1.y,b1.z,b1.w};
#pragma unroll
            for (int i = 0; i < 8; ++i)
#pragma unroll
                for (int j = 0; j < 8; ++j) acc[i][j] += am[i] * bn[j];
        }
        __syncthreads();
    }

    // epilogue: + bias, store
    float wb[8];
#pragma unroll
    for (int j = 0; j < 8; ++j) {
        int n = n0 + ((j < 4) ? (tx*4 + j) : (64 + tx*4 + j - 4));
        wb[j] = Wb[n];
    }
#pragma unroll
    for (int i = 0; i < 8; ++i) {
        int m = m0 + ((i < 4) ? (ty*4 + i) : (64 + ty*4 + i - 4));
        size_t base = (size_t)m * NG + n0;
        if (!use_bf) {
            float4 v0, v1;
            v0.x = acc[i][0]+wb[0]; v0.y = acc[i][1]+wb[1];
            v0.z = acc[i][2]+wb[2]; v0.w = acc[i][3]+wb[3];
            v1.x = acc[i][4]+wb[4]; v1.y = acc[i][5]+wb[5];
            v1.z = acc[i][6]+wb[6]; v1.w = acc[i][7]+wb[7];
            *(float4*)&out_f[base + tx*4]      = v0;
            *(float4*)&out_f[base + 64 + tx*4] = v1;
        } else {
#pragma unroll
            for (int j = 0; j < 8; ++j) {
                int nn = (j < 4) ? (tx*4 + j) : (64 + tx*4 + j - 4);
                out_b[base + nn] = __float2bfloat16(acc[i][j] + wb[j]);
            }
        }
    }
}

// ---------------------------------------------------------------------------
// Phase 2: persistent cooperative LSTM scan.
// 512 WGs x 256 threads, 2 WGs/CU.  WG owns 2 hidden units (8 U gate-rows,
// 32 KB fp32 in LDS, transposed [k][8]) x all 64 batches.
// Thread (w=tid>>6 wave, hp=(tid>>5)&1, g=(tid>>3)&3 gate, bg=tid&7):
//   kseg = 2w+hp (8 segs x 128 k, split-K), 2 rows (units 0,1 of gate g),
//   8 batches -> 16 fp32 accumulators.
// h lives in d_ws transposed [k][b], double-buffered by step parity; each wave
// stages its own kseg's 8-k window into a wave-private LDS region (no barriers
// in the K-loop).  +4-word parity offset per half makes the bg-strided b128
// reads 2-way (free) instead of 4-way conflicted.
// c stays in registers for all 512 steps.  One grid.sync() per step.
// ---------------------------------------------------------------------------
#define UT_OFF   0                    // 1024*8 = 8192 words
#define HBUF_OFF 8192                 // 4 waves * 1032 words = 4128
#define RED_OFF  (8192 + 4128)        // [4][8][66] = 2112 words
#define SMEM_WORDS (8192 + 4128 + 2112)
#define SMEM_BYTES (SMEM_WORDS * 4)   // 57,728 B  (< 64 KB)

#define HSCR_WORDS 65536              // one h buffer: [1024 k][64 b]

__global__ __launch_bounds__(256, 2) void lstm_scan(
    const float* __restrict__ xw_f,
    const __hip_bfloat16* __restrict__ xw_b,
    int use_bf,
    const float* __restrict__ Uw,     // [4096,1024]
    const float* __restrict__ h0,     // [64,1024]
    const float* __restrict__ c0,     // [64,1024]
    float* __restrict__ out,          // hidden_seq | h_t | c_t
    float* __restrict__ h_scr)        // [2][1024][64]
{
    extern __shared__ float smem[];
    cg::grid_group grid = cg::this_grid();

    const int tid  = threadIdx.x;
    const int lane = tid & 63;
    const int w    = tid >> 6;          // wave 0..3
    const int hp   = (tid >> 5) & 1;    // half-wave -> kseg parity
    const int kseg = 2*w + hp;          // 0..7 (128 k each)
    const int g    = (tid >> 3) & 3;    // gate 0..3 (i,f,g,o)
    const int bg   = tid & 7;           // batch octet
    const int u0   = blockIdx.x * 2;    // this WG's 2 hidden units

    // ---- one-time: stage U rows (transposed [k][r]) ----
#pragma unroll
    for (int r = 0; r < 8; ++r) {
        int q  = r >> 1;    // gate
        int uu = r & 1;     // unit
        const float4* grow = (const float4*)(Uw + (size_t)(q*HDIM + u0 + uu) * IDIM);
        float4 v = grow[tid];           // k = tid*4 .. +4
        smem[UT_OFF + (tid*4+0)*8 + r] = v.x;
        smem[UT_OFF + (tid*4+1)*8 + r] = v.y;
        smem[UT_OFF + (tid*4+2)*8 + r] = v.z;
        smem[UT_OFF + (tid*4+3)*8 + r] = v.w;
    }

    // ---- one-time: transpose h0 into h_scr[0] ([k][b]) ----
    int gtid = blockIdx.x * 256 + tid;
    if (gtid < BATCH * HDIM) {
        int b = gtid & 63;
        int k = gtid >> 6;
        h_scr[k*64 + b] = h0[(size_t)b * HDIM + k];
    }

    // ---- one-time: c0 into registers (elementwise threads) ----
    const int eb = tid >> 1;    // batch   (elementwise mapping, tid<128)
    const int eu = tid & 1;     // unit
    float creg = 0.f;
    if (tid < 128) creg = c0[(size_t)eb * HDIM + u0 + eu];

    // staging offset templates (per lane, constant over steps)
    int gsrc[4], ldst[4];
#pragma unroll
    for (int j = 0; j < 4; ++j) {
        int half = j >> 1, part = j & 1;
        gsrc[j] = ((2*w + half) * 128) * 64 + part * 256 + lane * 4;
        ldst[j] = HBUF_OFF + w * 1032 + half * 516 + part * 256 + lane * 4;
    }
    const float* hb = smem + HBUF_OFF + w * 1032 + hp * 516;
    const float* ut = smem + UT_OFF;

    grid.sync();   // h_scr[0] + LDS ready everywhere

    for (int t = 0; t < S_LEN; ++t) {
        const int cur = t & 1;
        const int nxt = cur ^ 1;

        // prefetch this step's xW gate values (independent of h)
        float xf[4] = {0.f, 0.f, 0.f, 0.f};
        if (tid < 128) {
            size_t base = ((size_t)t * BATCH + eb) * NG + u0 + eu;
            if (!use_bf) {
#pragma unroll
                for (int q = 0; q < 4; ++q) xf[q] = xw_f[base + q*HDIM];
            } else {
#pragma unroll
                for (int q = 0; q < 4; ++q) xf[q] = __bfloat162float(xw_b[base + q*HDIM]);
            }
        }

        float acc0[8], acc1[8];
#pragma unroll
        for (int j = 0; j < 8; ++j) { acc0[j] = 0.f; acc1[j] = 0.f; }

        const float* hsrc = h_scr + cur * HSCR_WORDS;

        for (int rnd = 0; rnd < 16; ++rnd) {
            // wave-private staging of this wave's two kseg windows (8 k each)
            const float* src = hsrc + rnd * 512;
#pragma unroll
            for (int j = 0; j < 4; ++j) {
                float4 v = *(const float4*)(src + gsrc[j]);
                *(float4*)(smem + ldst[j]) = v;
            }

            const int kbase = kseg * 128 + rnd * 8;
#pragma unroll
            for (int kk = 0; kk < 8; ++kk) {
                float2 uv = *(const float2*)(ut + (kbase + kk) * 8 + 2*g);
                const float* hr = hb + kk * 64 + bg * 8;
                float4 ha = *(const float4*)(hr);
                float4 hc = *(const float4*)(hr + 4);
                acc0[0] += uv.x * ha.x;  acc0[1] += uv.x * ha.y;
                acc0[2] += uv.x * ha.z;  acc0[3] += uv.x * ha.w;
                acc0[4] += uv.x * hc.x;  acc0[5] += uv.x * hc.y;
                acc0[6] += uv.x * hc.z;  acc0[7] += uv.x * hc.w;
                acc1[0] += uv.y * ha.x;  acc1[1] += uv.y * ha.y;
                acc1[2] += uv.y * ha.z;  acc1[3] += uv.y * ha.w;
                acc1[4] += uv.y * hc.x;  acc1[5] += uv.y * hc.y;
                acc1[6] += uv.y * hc.z;  acc1[7] += uv.y * hc.w;
            }
        }

        // reduce kseg pairs (lanes l <-> l^32 share (g,bg))
#pragma unroll
        for (int j = 0; j < 8; ++j) {
            acc0[j] += __shfl_xor(acc0[j], 32, 64);
            acc1[j] += __shfl_xor(acc1[j], 32, 64);
        }
        if (hp == 0) {
#pragma unroll
            for (int j = 0; j < 8; ++j) {
                smem[RED_OFF + (w*8 + g*2 + 0)*66 + bg*8 + j] = acc0[j];
                smem[RED_OFF + (w*8 + g*2 + 1)*66 + bg*8 + j] = acc1[j];
            }
        }
        __syncthreads();

        if (tid < 128) {
            float s[4];
#pragma unroll
            for (int q = 0; q < 4; ++q) {
                float v = xf[q];
#pragma unroll
                for (int ww = 0; ww < 4; ++ww)
                    v += smem[RED_OFF + (ww*8 + q*2 + eu)*66 + eb];
                s[q] = v;
            }
            float ig = 1.f / (1.f + expf(-s[0]));
            float fg = 1.f / (1.f + expf(-s[1]));
            float gv = tanhf(s[2]);
            float og = 1.f / (1.f + expf(-s[3]));
            creg = fg * creg + ig * gv;
            float hv = og * tanhf(creg);

            out[(size_t)t * 65536 + eb * HDIM + u0 + eu] = hv;
            h_scr[nxt * HSCR_WORDS + (u0 + eu) * 64 + eb] = hv;
            if (t == S_LEN - 1) {
                out[33554432u + eb * HDIM + u0 + eu] = hv;    // h_t
                out[33619968u + eb * HDIM + u0 + eu] = creg;  // c_t
            }
        }
        __threadfence();
        grid.sync();
    }
}

// ---------------------------------------------------------------------------
extern "C" void kernel_launch(void* const* d_in, const int* in_sizes, int n_in,
                              void* d_out, int out_size, void* d_ws, size_t ws_size,
                              hipStream_t stream) {
    const float* x   = (const float*)d_in[0];
    const float* h0  = (const float*)d_in[1];
    const float* c0  = (const float*)d_in[2];
    const float* Ww  = (const float*)d_in[3];
    const float* Wb  = (const float*)d_in[4];
    const float* Uw  = (const float*)d_in[5];
    float* out = (float*)d_out;

    const size_t xw_f32_bytes = (size_t)MROWS * NG * 4;        // 512 MB
    const size_t hscr_bytes   = (size_t)2 * HSCR_WORDS * 4;    // 512 KB
    const int use_bf = (ws_size < xw_f32_bytes + hscr_bytes) ? 1 : 0;
    const size_t xw_bytes = use_bf ? (xw_f32_bytes / 2) : xw_f32_bytes;

    float* xw_f = (float*)d_ws;
    __hip_bfloat16* xw_b = (__hip_bfloat16*)d_ws;
    float* h_scr = (float*)((char*)d_ws + xw_bytes);

    // Phase 1: input projection GEMM
    xw_gemm<<<dim3(NG/128, MROWS/128), dim3(256), 0, stream>>>(
        x, Ww, Wb, xw_f, xw_b, use_bf);

    // Phase 2: persistent cooperative scan
    const float* xwf_c = xw_f;
    const __hip_bfloat16* xwb_c = xw_b;
    int ub = use_bf;
    void* args[] = { (void*)&xwf_c, (void*)&xwb_c, (void*)&ub,
                     (void*)&Uw, (void*)&h0, (void*)&c0,
                     (void*)&out, (void*)&h_scr };
    hipLaunchCooperativeKernel((void*)lstm_scan, dim3(512), dim3(256),
                               args, SMEM_BYTES, stream);
}

// Round 4
// 30309.918 us; speedup vs baseline: 2.2773x; 2.2773x over previous
//
#include <hip/hip_runtime.h>
#include <hip/hip_bf16.h>

// Problem constants
#define S_LEN 512
#define BATCH 64
#define IDIM 1024
#define HDIM 1024
#define NG   4096              // 4*H
#define MROWS (S_LEN*BATCH)    // 32768
#define NWG  512               // scan workgroups

// ---------------------------------------------------------------------------
// Phase 1: xW[s,b,g] = sum_i x[s,b,i] * W_w[g,i] + W_b[g]
// ---------------------------------------------------------------------------
__global__ __launch_bounds__(256) void xw_gemm(
    const float* __restrict__ X,            // [32768,1024]
    const float* __restrict__ Wg,           // [4096,1024]
    const float* __restrict__ Wb,           // [4096]
    float* __restrict__ out_f,              // [32768,4096] (if !use_bf)
    __hip_bfloat16* __restrict__ out_b,     // same, bf16 (if use_bf)
    int use_bf)
{
    __shared__ float As[16][128];   // [k][m]
    __shared__ float Bs[16][128];   // [k][n]

    const int tid = threadIdx.x;
    const int tx = tid & 15;        // n-tile
    const int ty = tid >> 4;        // m-tile
    const int m0 = blockIdx.y * 128;
    const int n0 = blockIdx.x * 128;

    float acc[8][8];
#pragma unroll
    for (int i = 0; i < 8; ++i)
#pragma unroll
        for (int j = 0; j < 8; ++j) acc[i][j] = 0.f;

    for (int k0 = 0; k0 < IDIM; k0 += 16) {
#pragma unroll
        for (int c = 0; c < 2; ++c) {
            int chunk = tid + c * 256;
            int row = chunk >> 2;
            int kq  = chunk & 3;
            float4 av = *(const float4*)&X [(size_t)(m0 + row) * IDIM + k0 + kq * 4];
            float4 bv = *(const float4*)&Wg[(size_t)(n0 + row) * IDIM + k0 + kq * 4];
            As[kq*4+0][row] = av.x; As[kq*4+1][row] = av.y;
            As[kq*4+2][row] = av.z; As[kq*4+3][row] = av.w;
            Bs[kq*4+0][row] = bv.x; Bs[kq*4+1][row] = bv.y;
            Bs[kq*4+2][row] = bv.z; Bs[kq*4+3][row] = bv.w;
        }
        __syncthreads();

#pragma unroll
        for (int kk = 0; kk < 16; ++kk) {
            float4 a0 = *(const float4*)&As[kk][ty*4];
            float4 a1 = *(const float4*)&As[kk][64 + ty*4];
            float4 b0 = *(const float4*)&Bs[kk][tx*4];
            float4 b1 = *(const float4*)&Bs[kk][64 + tx*4];
            float am[8] = {a0.x,a0.y,a0.z,a0.w,a1.x,a1.y,a1.z,a1.w};
            float bn[8] = {b0.x,b0.y,b0.z,b0.w,b1.x,b1.y,b1.z,b1.w};
#pragma unroll
            for (int i = 0; i < 8; ++i)
#pragma unroll
                for (int j = 0; j < 8; ++j) acc[i][j] += am[i] * bn[j];
        }
        __syncthreads();
    }

    float wb[8];
#pragma unroll
    for (int j = 0; j < 8; ++j) {
        int n = n0 + ((j < 4) ? (tx*4 + j) : (64 + tx*4 + j - 4));
        wb[j] = Wb[n];
    }
#pragma unroll
    for (int i = 0; i < 8; ++i) {
        int m = m0 + ((i < 4) ? (ty*4 + i) : (64 + ty*4 + i - 4));
        size_t base = (size_t)m * NG + n0;
        if (!use_bf) {
            float4 v0, v1;
            v0.x = acc[i][0]+wb[0]; v0.y = acc[i][1]+wb[1];
            v0.z = acc[i][2]+wb[2]; v0.w = acc[i][3]+wb[3];
            v1.x = acc[i][4]+wb[4]; v1.y = acc[i][5]+wb[5];
            v1.z = acc[i][6]+wb[6]; v1.w = acc[i][7]+wb[7];
            *(float4*)&out_f[base + tx*4]      = v0;
            *(float4*)&out_f[base + 64 + tx*4] = v1;
        } else {
#pragma unroll
            for (int j = 0; j < 8; ++j) {
                int nn = (j < 4) ? (tx*4 + j) : (64 + tx*4 + j - 4);
                out_b[base + nn] = __float2bfloat16(acc[i][j] + wb[j]);
            }
        }
    }
}

// ---------------------------------------------------------------------------
// Phase 2: persistent scan with SELF-VALIDATING h slots.
// Each h element is one 8-byte atom: (fp32 value | uint32 step-tag).
// Indivisible 8B relaxed agent atomics => a consumer can never see a torn or
// mis-ordered (value,tag) pair; it spin-reloads any slot whose tag != t.
// Correct under ANY store/flag ordering (round 2/3's failure mode: flag
// visible before data). The relaxed counter barrier remains ONLY for WAR
// protection of the double buffer (fetch_add issues after __syncthreads
// retires this WG's loads — a purely local guarantee, fence-free).
// Tag schedule: h input to step t carries tag t in buffer t&1; poison
// 0xAAAAAAAA never matches; t+2 cannot appear before all WGs leave step t.
// ---------------------------------------------------------------------------
#define UT_OFF   0                        // 1024*8 = 8192 words
#define HBUF_OFF 8192                     // 4 waves * 1032 words = 4128
#define RED_OFF  (8192 + 4128)            // [4][8][66] = 2112 words
#define SMEM_WORDS (RED_OFF + 2112)       // 14432 words = 57,728 B

#define HSLOTS 65536                      // one h buffer: [1024 k][64 b] slots

typedef unsigned long long u64;

__device__ __forceinline__ u64 h_ld(const u64* p) {
    return __hip_atomic_load(p, __ATOMIC_RELAXED, __HIP_MEMORY_SCOPE_AGENT);
}
__device__ __forceinline__ void h_st(u64* p, float v, unsigned tag) {
    union { float f; unsigned u; } c; c.f = v;
    u64 s = ((u64)tag << 32) | (u64)c.u;
    __hip_atomic_store(p, s, __ATOMIC_RELAXED, __HIP_MEMORY_SCOPE_AGENT);
}

__global__ __launch_bounds__(256, 2) void lstm_scan(
    const float* __restrict__ xw_f,
    const __hip_bfloat16* __restrict__ xw_b,
    int use_bf,
    const float* __restrict__ Uw,     // [4096,1024]
    const float* __restrict__ h0,     // [64,1024]
    const float* __restrict__ c0,     // [64,1024]
    float* __restrict__ out,          // hidden_seq | h_t | c_t
    u64* __restrict__ h_scr,          // [2][1024][64] tagged slots
    unsigned* __restrict__ flags)     // [S_LEN+1] arrival counters (zeroed)
{
    __shared__ float smem[SMEM_WORDS];

    const int tid  = threadIdx.x;
    const int lane = tid & 63;
    const int w    = tid >> 6;          // wave 0..3
    const int hp   = (tid >> 5) & 1;    // half-wave -> kseg parity
    const int kseg = 2*w + hp;          // 0..7 (128 k each)
    const int g    = (tid >> 3) & 3;    // gate 0..3 (i,f,g,o)
    const int bg   = tid & 7;           // batch octet
    const int u0   = blockIdx.x * 2;    // this WG's 2 hidden units

    // ---- one-time: stage U rows (transposed [k][r]) ----
#pragma unroll
    for (int r = 0; r < 8; ++r) {
        int q  = r >> 1;    // gate
        int uu = r & 1;     // unit
        const float4* grow = (const float4*)(Uw + (size_t)(q*HDIM + u0 + uu) * IDIM);
        float4 v = grow[tid];
        smem[UT_OFF + (tid*4+0)*8 + r] = v.x;
        smem[UT_OFF + (tid*4+1)*8 + r] = v.y;
        smem[UT_OFF + (tid*4+2)*8 + r] = v.z;
        smem[UT_OFF + (tid*4+3)*8 + r] = v.w;
    }

    // ---- one-time: transpose h0 into buffer 0 with tag 0 ----
    int gtid = blockIdx.x * 256 + tid;
    if (gtid < BATCH * HDIM) {
        int b = gtid & 63;
        int k = gtid >> 6;
        h_st(&h_scr[k*64 + b], h0[(size_t)b * HDIM + k], 0u);
    }

    // ---- one-time: c0 into registers ----
    const int eb = tid >> 1;    // batch (elementwise mapping, tid<128)
    const int eu = tid & 1;     // unit
    float creg = 0.f;
    if (tid < 128) creg = c0[(size_t)eb * HDIM + u0 + eu];

    // per-lane constant offsets (slot units)
    int gbase[4], ldsoff[4];
#pragma unroll
    for (int j = 0; j < 4; ++j) {
        int half = j >> 1, part = j & 1;
        gbase[j]  = (2*w + half) * 8192 + part * 256 + lane * 4;
        ldsoff[j] = HBUF_OFF + w * 1032 + half * 516 + part * 256 + lane * 4;
    }
    const float* hb = smem + HBUF_OFF + w * 1032 + hp * 516;
    const float* ut = smem + UT_OFF;

    // init writes retired locally, then announce
    __syncthreads();
    if (tid == 0)
        __hip_atomic_fetch_add(&flags[0], 1u, __ATOMIC_RELAXED,
                               __HIP_MEMORY_SCOPE_AGENT);

    for (int t = 0; t < S_LEN; ++t) {
        const int cur = t & 1;
        const int nxt = cur ^ 1;
        const unsigned tagv = (unsigned)t;

        // xW prefetch (independent of h) — in flight during the barrier wait
        float xf[4] = {0.f, 0.f, 0.f, 0.f};
        if (tid < 128) {
            size_t base = ((size_t)t * BATCH + eb) * NG + u0 + eu;
            if (!use_bf) {
#pragma unroll
                for (int q = 0; q < 4; ++q) xf[q] = xw_f[base + q*HDIM];
            } else {
#pragma unroll
                for (int q = 0; q < 4; ++q) xf[q] = __bfloat162float(xw_b[base + q*HDIM]);
            }
        }

        // WAR barrier: all WGs finished *reading* buffer nxt's old generation
        if (tid == 0) {
            while (__hip_atomic_load(&flags[t], __ATOMIC_RELAXED,
                                     __HIP_MEMORY_SCOPE_AGENT) < NWG)
                __builtin_amdgcn_s_sleep(1);
        }
        __syncthreads();

        float acc0[8], acc1[8];
#pragma unroll
        for (int j = 0; j < 8; ++j) { acc0[j] = 0.f; acc1[j] = 0.f; }

        const u64* hsrc = h_scr + (size_t)cur * HSLOTS;

        // prefetch round 0 (16 tagged slots per lane)
        u64 pr[16];
#pragma unroll
        for (int j = 0; j < 4; ++j)
#pragma unroll
            for (int i = 0; i < 4; ++i)
                pr[j*4+i] = h_ld(hsrc + gbase[j] + i);

        for (int rnd = 0; rnd < 16; ++rnd) {
            // consume: spin any stale tag, stage values into wave-private LDS
#pragma unroll
            for (int j = 0; j < 4; ++j) {
                float v4[4];
#pragma unroll
                for (int i = 0; i < 4; ++i) {
                    u64 s = pr[j*4+i];
                    while (__builtin_expect((unsigned)(s >> 32) != tagv, 0))
                        s = h_ld(hsrc + gbase[j] + rnd * 512 + i);
                    union { unsigned u; float f; } c; c.u = (unsigned)s;
                    v4[i] = c.f;
                }
                *(float4*)(smem + ldsoff[j]) = make_float4(v4[0], v4[1], v4[2], v4[3]);
            }

            // prefetch next round (in flight during this round's FMAs)
            if (rnd < 15) {
#pragma unroll
                for (int j = 0; j < 4; ++j)
#pragma unroll
                    for (int i = 0; i < 4; ++i)
                        pr[j*4+i] = h_ld(hsrc + gbase[j] + (rnd + 1) * 512 + i);
            }

            const int kbase = kseg * 128 + rnd * 8;
#pragma unroll
            for (int kk = 0; kk < 8; ++kk) {
                float2 uv = *(const float2*)(ut + (kbase + kk) * 8 + 2*g);
                const float* hr = hb + kk * 64 + bg * 8;
                float4 ha = *(const float4*)(hr);
                float4 hc = *(const float4*)(hr + 4);
                acc0[0] += uv.x * ha.x;  acc0[1] += uv.x * ha.y;
                acc0[2] += uv.x * ha.z;  acc0[3] += uv.x * ha.w;
                acc0[4] += uv.x * hc.x;  acc0[5] += uv.x * hc.y;
                acc0[6] += uv.x * hc.z;  acc0[7] += uv.x * hc.w;
                acc1[0] += uv.y * ha.x;  acc1[1] += uv.y * ha.y;
                acc1[2] += uv.y * ha.z;  acc1[3] += uv.y * ha.w;
                acc1[4] += uv.y * hc.x;  acc1[5] += uv.y * hc.y;
                acc1[6] += uv.y * hc.z;  acc1[7] += uv.y * hc.w;
            }
        }

        // reduce kseg pairs (lanes l <-> l^32 share (g,bg))
#pragma unroll
        for (int j = 0; j < 8; ++j) {
            acc0[j] += __shfl_xor(acc0[j], 32, 64);
            acc1[j] += __shfl_xor(acc1[j], 32, 64);
        }
        if (hp == 0) {
#pragma unroll
            for (int j = 0; j < 8; ++j) {
                smem[RED_OFF + (w*8 + g*2 + 0)*66 + bg*8 + j] = acc0[j];
                smem[RED_OFF + (w*8 + g*2 + 1)*66 + bg*8 + j] = acc1[j];
            }
        }
        __syncthreads();

        if (tid < 128) {
            float s[4];
#pragma unroll
            for (int q = 0; q < 4; ++q) {
                float v = xf[q];
#pragma unroll
                for (int ww = 0; ww < 4; ++ww)
                    v += smem[RED_OFF + (ww*8 + q*2 + eu)*66 + eb];
                s[q] = v;
            }
            float ig = 1.f / (1.f + expf(-s[0]));
            float fg = 1.f / (1.f + expf(-s[1]));
            float gv = tanhf(s[2]);
            float og = 1.f / (1.f + expf(-s[3]));
            creg = fg * creg + ig * gv;
            float hv = og * tanhf(creg);

            out[(size_t)t * 65536 + eb * HDIM + u0 + eu] = hv;
            h_st(&h_scr[(size_t)nxt * HSLOTS + (u0 + eu) * 64 + eb],
                 hv, (unsigned)(t + 1));
            if (t == S_LEN - 1) {
                out[33554432u + eb * HDIM + u0 + eu] = hv;    // h_t
                out[33619968u + eb * HDIM + u0 + eu] = creg;  // c_t
            }
        }

        // local retire of this WG's loads/stores, then arrival (WAR only)
        __syncthreads();
        if (tid == 0)
            __hip_atomic_fetch_add(&flags[t+1], 1u, __ATOMIC_RELAXED,
                                   __HIP_MEMORY_SCOPE_AGENT);
    }
}

// ---------------------------------------------------------------------------
extern "C" void kernel_launch(void* const* d_in, const int* in_sizes, int n_in,
                              void* d_out, int out_size, void* d_ws, size_t ws_size,
                              hipStream_t stream) {
    const float* x   = (const float*)d_in[0];
    const float* h0  = (const float*)d_in[1];
    const float* c0  = (const float*)d_in[2];
    const float* Ww  = (const float*)d_in[3];
    const float* Wb  = (const float*)d_in[4];
    const float* Uw  = (const float*)d_in[5];
    float* out = (float*)d_out;

    const size_t xw_f32_bytes = (size_t)MROWS * NG * 4;        // 512 MB
    const size_t hscr_bytes   = (size_t)2 * HSLOTS * 8;        // 1 MB
    const size_t flag_bytes   = 4096;
    const int use_bf = (ws_size < xw_f32_bytes + hscr_bytes + flag_bytes) ? 1 : 0;
    const size_t xw_bytes = use_bf ? (xw_f32_bytes / 2) : xw_f32_bytes;

    float* xw_f = (float*)d_ws;
    __hip_bfloat16* xw_b = (__hip_bfloat16*)d_ws;
    u64* h_scr = (u64*)((char*)d_ws + xw_bytes);
    unsigned* flags = (unsigned*)((char*)d_ws + xw_bytes + hscr_bytes);

    // zero the per-step arrival counters (ws is re-poisoned before every call)
    hipMemsetAsync(flags, 0, flag_bytes, stream);

    // Phase 1: input projection GEMM
    xw_gemm<<<dim3(NG/128, MROWS/128), dim3(256), 0, stream>>>(
        x, Ww, Wb, xw_f, xw_b, use_bf);

    // Phase 2: persistent scan. Cooperative launch for guaranteed
    // co-residency; if validation rejects it, plain launch (512 WGs at
    // 2 WG/CU exactly fill 256 CUs -> de-facto co-resident).
    const float* xwf_c = xw_f;
    const __hip_bfloat16* xwb_c = xw_b;
    int ub = use_bf;
    void* args[] = { (void*)&xwf_c, (void*)&xwb_c, (void*)&ub,
                     (void*)&Uw, (void*)&h0, (void*)&c0,
                     (void*)&out, (void*)&h_scr, (void*)&flags };
    hipError_t err = hipLaunchCooperativeKernel((void*)lstm_scan, dim3(NWG),
                                                dim3(256), args, 0, stream);
    if (err != hipSuccess) {
        lstm_scan<<<dim3(NWG), dim3(256), 0, stream>>>(
            xwf_c, xwb_c, ub, Uw, h0, c0, out, h_scr, flags);
    }
}